// Round 1
// baseline (1109.798 us; speedup 1.0000x reference)
//
#include <hip/hip_runtime.h>

#define T 128
#define C 20
#define KQ 100
#define NTHREADS 256
#define SCALE 0.08838834764831845f   // 1/sqrt(128)

// One block per batch. All per-batch tensors staged in LDS (154 KB).
// k/q stored transposed kT[d*T + i] so the hot score loops are
// conflict-free: per-lane operand at lane-consecutive addresses,
// shared operand as wave-uniform broadcast (merges to ds_read_b128).
__global__ __launch_bounds__(NTHREADS) void sa_fused(
    const float* __restrict__ x,
    const float* __restrict__ Wk, const float* __restrict__ bk,
    const float* __restrict__ Wq, const float* __restrict__ bq,
    const float* __restrict__ Wv, const float* __restrict__ bv,
    float* __restrict__ y)
{
    __shared__ float xs[T * C];        // 2560 f
    __shared__ float kT[KQ * T];       // 12800 f, kT[d*T + i]
    __shared__ float qT[KQ * T];       // 12800 f
    __shared__ float vs[T * C];        // 2560 f
    __shared__ float Wks[C * KQ];      // 2000 f
    __shared__ float Wqs[C * KQ];      // 2000 f
    __shared__ float Wvs[C * C];       // 400 f
    __shared__ float bks[KQ];
    __shared__ float bqs[KQ];
    __shared__ float bvs[C];
    __shared__ float linv[T];          // 1/colsum per column j
    __shared__ float lpart[4][T];      // per-wave partial column sums
    __shared__ float ys[T * C];        // output accumulator (init: residual)

    const int tid = threadIdx.x;
    const int b   = blockIdx.x;
    const float* xb = x + (size_t)b * (T * C);

    // ---- stage x + weights ----
    for (int idx = tid; idx < T * C; idx += NTHREADS) xs[idx] = xb[idx];
    for (int idx = tid; idx < C * KQ; idx += NTHREADS) { Wks[idx] = Wk[idx]; Wqs[idx] = Wq[idx]; }
    for (int idx = tid; idx < C * C; idx += NTHREADS) Wvs[idx] = Wv[idx];
    if (tid < KQ) { bks[tid] = bk[tid]; bqs[tid] = bq[tid]; }
    if (tid < C)  bvs[tid] = bv[tid];
    __syncthreads();

    // ---- projections: thread (i = tid>>1, h = tid&1); x row cached in regs ----
    {
        const int i = tid >> 1;
        const int h = tid & 1;
        float xr[C];
        #pragma unroll
        for (int c = 0; c < C; ++c) xr[c] = xs[i * C + c];

        #pragma unroll 1
        for (int n = 0; n < KQ / 2; ++n) {
            const int kk = h * (KQ / 2) + n;
            float sk = bks[kk];
            float sq = bqs[kk];
            #pragma unroll
            for (int c = 0; c < C; ++c) {
                sk += xr[c] * Wks[c * KQ + kk];
                sq += xr[c] * Wqs[c * KQ + kk];
            }
            kT[kk * T + i] = sk > 0.f ? sk : (__expf(sk) - 1.f);   // ELU
            qT[kk * T + i] = sq > 0.f ? sq : (__expf(sq) - 1.f);
        }
        #pragma unroll 1
        for (int n = 0; n < C / 2; ++n) {
            const int d = h * (C / 2) + n;
            float sv = bvs[d];
            #pragma unroll
            for (int c = 0; c < C; ++c) sv += xr[c] * Wvs[c * C + d];
            const float e2 = __expf(2.f * sv);                     // tanh; inf-safe -> 1
            vs[i * C + d] = 1.f - 2.f / (e2 + 1.f);
        }
    }
    // init output accumulator with residual
    for (int idx = tid; idx < T * C; idx += NTHREADS) ys[idx] = xs[idx];
    __syncthreads();

    // ---- pass A: column sums of exp(s) (softmax axis=1 denominators) ----
    // wave (qtr) owns 32 rows; lane owns columns {lane, lane+64}
    {
        const int j0  = tid & 63;
        const int j1  = j0 + 64;
        const int qtr = tid >> 6;      // wave id, uniform
        float l0 = 0.f, l1 = 0.f;
        #pragma unroll 1
        for (int ib = 0; ib < 4; ++ib) {
            const int i0 = qtr * 32 + ib * 8;
            float a0[8], a1[8];
            #pragma unroll
            for (int r = 0; r < 8; ++r) { a0[r] = 0.f; a1[r] = 0.f; }
            #pragma unroll 2
            for (int d = 0; d < KQ; ++d) {
                const float qa = qT[d * T + j0];
                const float qb = qT[d * T + j1];
                #pragma unroll
                for (int r = 0; r < 8; ++r) {
                    const float kv = kT[d * T + i0 + r];   // wave-uniform broadcast
                    a0[r] += kv * qa;
                    a1[r] += kv * qb;
                }
            }
            #pragma unroll
            for (int r = 0; r < 8; ++r) {
                l0 += __expf(a0[r] * SCALE);
                l1 += __expf(a1[r] * SCALE);
            }
        }
        lpart[qtr][j0] = l0;
        lpart[qtr][j1] = l1;
    }
    __syncthreads();
    if (tid < T) {
        linv[tid] = 1.f / (lpart[0][tid] + lpart[1][tid] + lpart[2][tid] + lpart[3][tid]);
    }
    __syncthreads();

    // ---- pass B: y[i,:] = sum_j exp(s_ij)*linv[j] * v[j,:]  (+ residual in ys) ----
    // lane owns rows {lane, lane+64}; wave (h) owns 32 columns
    {
        const int ia = tid & 63;
        const int ib2 = ia + 64;
        const int h  = tid >> 6;       // j quarter, uniform per wave
        float ya[C], yb[C];
        #pragma unroll
        for (int d = 0; d < C; ++d) { ya[d] = 0.f; yb[d] = 0.f; }
        #pragma unroll 1
        for (int jb = 0; jb < 4; ++jb) {
            const int j0 = h * 32 + jb * 8;
            float s0[8], s1[8];
            #pragma unroll
            for (int r = 0; r < 8; ++r) { s0[r] = 0.f; s1[r] = 0.f; }
            #pragma unroll 2
            for (int d = 0; d < KQ; ++d) {
                const float ka = kT[d * T + ia];
                const float kb = kT[d * T + ib2];
                #pragma unroll
                for (int r = 0; r < 8; ++r) {
                    const float qv = qT[d * T + j0 + r];   // wave-uniform broadcast
                    s0[r] += ka * qv;
                    s1[r] += kb * qv;
                }
            }
            #pragma unroll
            for (int r = 0; r < 8; ++r) {
                const int j = j0 + r;
                const float li = linv[j];
                const float p0 = __expf(s0[r] * SCALE) * li;
                const float p1 = __expf(s1[r] * SCALE) * li;
                #pragma unroll
                for (int d = 0; d < C; ++d) {
                    const float vv = vs[j * C + d];        // wave-uniform broadcast
                    ya[d] += p0 * vv;
                    yb[d] += p1 * vv;
                }
            }
        }
        // 4 waves accumulate into ys in phases (no atomics)
        #pragma unroll 1
        for (int ph = 0; ph < 4; ++ph) {
            if (h == ph) {
                #pragma unroll
                for (int d = 0; d < C; ++d) {
                    ys[ia * C + d]  += ya[d];
                    ys[ib2 * C + d] += yb[d];
                }
            }
            __syncthreads();
        }
    }

    // ---- coalesced store ----
    float* yg = y + (size_t)b * (T * C);
    for (int idx = tid; idx < T * C; idx += NTHREADS) yg[idx] = ys[idx];
}

extern "C" void kernel_launch(void* const* d_in, const int* in_sizes, int n_in,
                              void* d_out, int out_size, void* d_ws, size_t ws_size,
                              hipStream_t stream) {
    const float* x  = (const float*)d_in[0];
    const float* Wk = (const float*)d_in[1];
    const float* bk = (const float*)d_in[2];
    const float* Wq = (const float*)d_in[3];
    const float* bq = (const float*)d_in[4];
    const float* Wv = (const float*)d_in[5];
    const float* bv = (const float*)d_in[6];
    float* y = (float*)d_out;
    const int B = in_sizes[0] / (T * C);   // 4096
    sa_fused<<<B, NTHREADS, 0, stream>>>(x, Wk, bk, Wq, bq, Wv, bv, y);
}

// Round 2
// 717.197 us; speedup vs baseline: 1.5474x; 1.5474x over previous
//
#include <hip/hip_runtime.h>

#define T 128
#define C 20
#define KQ 100
#define NTHREADS 256
#define SCALE 0.08838834764831845f   // 1/sqrt(128)
#define PSTRIDE 33                   // pchunk row stride (+1 pad: conflict-free consumer reads)

// One block per batch (1 block/CU, LDS-limited). Scores held in 64 regs/thread
// (8x8 tile, computed ONCE). Column softmax via LDS partial reduction.
// Normalized P staged through a 32-column LDS chunk buffer for the PV matmul.
__global__ __launch_bounds__(NTHREADS) void sa_fused(
    const float* __restrict__ x,
    const float* __restrict__ Wk, const float* __restrict__ bk,
    const float* __restrict__ Wq, const float* __restrict__ bq,
    const float* __restrict__ Wv, const float* __restrict__ bv,
    float* __restrict__ y)
{
    __shared__ float kT[KQ * T];        // 51200 B  kT[d*T + i]
    __shared__ float qT[KQ * T];        // 51200 B
    __shared__ float vs[T * C];         // 10240 B
    __shared__ float Wks[C * KQ];       // 8000 B
    __shared__ float Wqs[C * KQ];       // 8000 B
    __shared__ float Wvs[C * C];        // 1600 B
    __shared__ float bks[KQ];
    __shared__ float bqs[KQ];
    __shared__ float bvs[C];
    __shared__ float colpart[16][T];    // 8192 B   per-ty partial column sums
    __shared__ float linv[T];           // 512 B
    __shared__ float pchunk[T * PSTRIDE]; // 16896 B  normalized P, 32 j-columns at a time

    const int tid = threadIdx.x;
    const int b   = blockIdx.x;
    const float* xb = x + (size_t)b * (T * C);

    // ---- stage weights ----
    for (int idx = tid; idx < C * KQ; idx += NTHREADS) { Wks[idx] = Wk[idx]; Wqs[idx] = Wq[idx]; }
    for (int idx = tid; idx < C * C; idx += NTHREADS) Wvs[idx] = Wv[idx];
    if (tid < KQ) { bks[tid] = bk[tid]; bqs[tid] = bq[tid]; }
    if (tid < C)  bvs[tid] = bv[tid];
    __syncthreads();

    // ---- projections: thread (i = tid>>1, h = tid&1); x row read from global ----
    {
        const int i = tid >> 1;
        const int h = tid & 1;
        float xr[C];
        const float4* x4 = (const float4*)(xb + i * C);   // i*80B, 16B aligned
        #pragma unroll
        for (int w = 0; w < 5; ++w) ((float4*)xr)[w] = x4[w];

        #pragma unroll 1
        for (int n = 0; n < KQ / 2; ++n) {
            const int kk = h * (KQ / 2) + n;
            float sk = bks[kk];
            float sq = bqs[kk];
            #pragma unroll
            for (int c = 0; c < C; ++c) {
                sk += xr[c] * Wks[c * KQ + kk];
                sq += xr[c] * Wqs[c * KQ + kk];
            }
            kT[kk * T + i] = sk > 0.f ? sk : (__expf(sk) - 1.f);   // ELU
            qT[kk * T + i] = sq > 0.f ? sq : (__expf(sq) - 1.f);
        }
        #pragma unroll 1
        for (int n = 0; n < C / 2; ++n) {
            const int d = h * (C / 2) + n;
            float sv = bvs[d];
            #pragma unroll
            for (int c = 0; c < C; ++c) sv += xr[c] * Wvs[c * C + d];
            const float e2 = __expf(2.f * sv);                     // tanh; inf-safe -> 1
            vs[i * C + d] = 1.f - 2.f / (e2 + 1.f);
        }
    }
    __syncthreads();

    // ---- scores, computed ONCE into registers: thread (ty=tid>>4, tx=tid&15)
    //      owns rows i = ty*8..+8, cols j = tx*8..+8 ----
    const int tx = tid & 15;
    const int ty = tid >> 4;
    float acc[8][8];
    #pragma unroll
    for (int r = 0; r < 8; ++r)
        #pragma unroll
        for (int c = 0; c < 8; ++c) acc[r][c] = 0.f;

    #pragma unroll 2
    for (int d = 0; d < KQ; ++d) {
        float kv[8], qv[8];
        ((float4*)kv)[0] = *(const float4*)&kT[d * T + ty * 8];
        ((float4*)kv)[1] = *(const float4*)&kT[d * T + ty * 8 + 4];
        ((float4*)qv)[0] = *(const float4*)&qT[d * T + tx * 8];
        ((float4*)qv)[1] = *(const float4*)&qT[d * T + tx * 8 + 4];
        #pragma unroll
        for (int r = 0; r < 8; ++r)
            #pragma unroll
            for (int c = 0; c < 8; ++c)
                acc[r][c] += kv[r] * qv[c];
    }

    // exp + per-thread column sums
    {
        float cs[8];
        #pragma unroll
        for (int c = 0; c < 8; ++c) cs[c] = 0.f;
        #pragma unroll
        for (int r = 0; r < 8; ++r)
            #pragma unroll
            for (int c = 0; c < 8; ++c) {
                acc[r][c] = __expf(acc[r][c] * SCALE);
                cs[c] += acc[r][c];
            }
        *(float4*)&colpart[ty][tx * 8]     = ((float4*)cs)[0];
        *(float4*)&colpart[ty][tx * 8 + 4] = ((float4*)cs)[1];
    }
    __syncthreads();

    // column softmax denominators
    if (tid < T) {
        float s = 0.f;
        #pragma unroll
        for (int t = 0; t < 16; ++t) s += colpart[t][tid];
        linv[tid] = 1.f / s;
    }
    __syncthreads();

    // fold linv into the register tile
    {
        float lv[8];
        ((float4*)lv)[0] = *(const float4*)&linv[tx * 8];
        ((float4*)lv)[1] = *(const float4*)&linv[tx * 8 + 4];
        #pragma unroll
        for (int r = 0; r < 8; ++r)
            #pragma unroll
            for (int c = 0; c < 8; ++c) acc[r][c] *= lv[c];
    }

    // ---- PV matmul via 4 chunks of 32 j-columns staged in LDS ----
    const int i  = tid >> 1;
    const int h  = tid & 1;
    float yacc[10];
    #pragma unroll
    for (int d = 0; d < 10; ++d) yacc[d] = 0.f;

    #pragma unroll 1
    for (int cc = 0; cc < 4; ++cc) {
        if ((tx >> 2) == cc) {
            const int txl = tx & 3;
            #pragma unroll
            for (int r = 0; r < 8; ++r)
                #pragma unroll
                for (int c = 0; c < 8; ++c)
                    pchunk[(ty * 8 + r) * PSTRIDE + txl * 8 + c] = acc[r][c];
        }
        __syncthreads();

        const float* prow = &pchunk[i * PSTRIDE];
        #pragma unroll 4
        for (int j = 0; j < 32; ++j) {
            const float p = prow[j];
            const float2* v2 = (const float2*)&vs[(cc * 32 + j) * C + h * 10];  // 8B aligned
            #pragma unroll
            for (int w = 0; w < 5; ++w) {
                const float2 vv = v2[w];
                yacc[2 * w]     += p * vv.x;
                yacc[2 * w + 1] += p * vv.y;
            }
        }
        if (cc < 3) __syncthreads();
    }

    // ---- residual + store (thread covers 10 consecutive floats) ----
    {
        const float2* xr2 = (const float2*)(xb + i * C + h * 10);
        float2* yr2 = (float2*)(y + (size_t)b * (T * C) + i * C + h * 10);
        #pragma unroll
        for (int w = 0; w < 5; ++w) {
            float2 o = xr2[w];
            o.x += yacc[2 * w];
            o.y += yacc[2 * w + 1];
            yr2[w] = o;
        }
    }
}

extern "C" void kernel_launch(void* const* d_in, const int* in_sizes, int n_in,
                              void* d_out, int out_size, void* d_ws, size_t ws_size,
                              hipStream_t stream) {
    const float* x  = (const float*)d_in[0];
    const float* Wk = (const float*)d_in[1];
    const float* bk = (const float*)d_in[2];
    const float* Wq = (const float*)d_in[3];
    const float* bq = (const float*)d_in[4];
    const float* Wv = (const float*)d_in[5];
    const float* bv = (const float*)d_in[6];
    float* y = (float*)d_out;
    const int B = in_sizes[0] / (T * C);   // 4096
    sa_fused<<<B, NTHREADS, 0, stream>>>(x, Wk, bk, Wq, bq, Wv, bv, y);
}

// Round 3
// 273.869 us; speedup vs baseline: 4.0523x; 2.6188x over previous
//
#include <hip/hip_runtime.h>

#define T 128
#define C 20
#define KQ 100
#define NT 512
#define SCALE 0.08838834764831845f   // 1/sqrt(128)
#define LDK 136                      // bf16 row stride: 272 B = 16B-aligned, bank-balanced

typedef float  f32x4  __attribute__((ext_vector_type(4)));
typedef short  bf16x8 __attribute__((ext_vector_type(8)));

__device__ __forceinline__ short f2bf(float f) {
    unsigned u = __builtin_bit_cast(unsigned, f);
    unsigned r = (u + 0x7FFFu + ((u >> 16) & 1u)) >> 16;   // RNE
    return (short)r;
}

// One block per batch, 512 threads (8 waves), ~77 KB LDS -> 2 blocks/CU.
// Scores + PV on MFMA bf16; projections on VALU with wave-uniform weight
// reads (s_load path). P reuses the k buffer after the softmax barrier.
__global__ __launch_bounds__(NT, 4) void sa_fused(
    const float* __restrict__ x,
    const float* __restrict__ Wk, const float* __restrict__ bk,
    const float* __restrict__ Wq, const float* __restrict__ bq,
    const float* __restrict__ Wv, const float* __restrict__ bv,
    float* __restrict__ y)
{
    __shared__ __align__(16) short kp_lds[T * LDK];   // k (bf16, [i][d] pad128) -> later P [i][j]
    __shared__ __align__(16) short q_lds [T * LDK];   // q (bf16, [j][d] pad128)
    __shared__ __align__(16) short vT_lds[32 * LDK];  // v^T (bf16, [dd][j], rows 20..31 zero)
    __shared__ float linv[T];

    const int tid  = threadIdx.x;
    const int lane = tid & 63;
    const int w    = __builtin_amdgcn_readfirstlane(tid >> 6);  // wave id, force uniform
    const int quad = lane >> 4;
    const int l16  = lane & 15;
    const int b    = blockIdx.x;
    const float* xb = x + (size_t)b * (T * C);

    // ---- phase 1a: zero the pads (k/q cols 100..135, vT rows 20..31, linv) ----
    {
        unsigned* kz = (unsigned*)kp_lds;
        unsigned* qz = (unsigned*)q_lds;
        for (int idx = tid; idx < T * 18; idx += NT) {          // 18 dwords = cols 100..135
            const int r = idx / 18, c = idx % 18;
            const int off = r * (LDK / 2) + 50 + c;
            kz[off] = 0u; qz[off] = 0u;
        }
        unsigned* vz = (unsigned*)vT_lds;
        for (int idx = tid; idx < 12 * (LDK / 2); idx += NT) {  // rows 20..31, all cols
            const int r = 20 + idx / (LDK / 2), c = idx % (LDK / 2);
            vz[r * (LDK / 2) + c] = 0u;
        }
        if (tid < T) linv[tid] = 0.f;
    }

    // ---- phase 1b: projections (VALU). wave -> (row half, kk quarter) ----
    {
        const int half = __builtin_amdgcn_readfirstlane(w >> 2);  // 0..1
        const int h    = __builtin_amdgcn_readfirstlane(w & 3);   // 0..3 (kk quarter)
        const int i    = (half << 6) | lane;                      // row 0..127
        float xr[C];
        const float4* x4 = (const float4*)(xb + i * C);
        #pragma unroll
        for (int t = 0; t < 5; ++t) ((float4*)xr)[t] = x4[t];

        #pragma unroll 1
        for (int n = 0; n < 25; ++n) {
            const int kk = h * 25 + n;                            // wave-uniform
            float sk = bk[kk];
            float sq = bq[kk];
            #pragma unroll
            for (int c = 0; c < C; ++c) {
                sk += xr[c] * Wk[c * KQ + kk];                    // s_load (uniform)
                sq += xr[c] * Wq[c * KQ + kk];
            }
            sk = sk > 0.f ? sk : (__expf(sk) - 1.f);              // ELU
            sq = sq > 0.f ? sq : (__expf(sq) - 1.f);
            kp_lds[i * LDK + kk] = f2bf(sk);
            q_lds [i * LDK + kk] = f2bf(sq);
        }
        #pragma unroll 1
        for (int n = 0; n < 5; ++n) {
            const int dd = h * 5 + n;                             // wave-uniform
            float sv = bv[dd];
            #pragma unroll
            for (int c = 0; c < C; ++c) sv += xr[c] * Wv[c * C + dd];
            const float e2 = __expf(2.f * sv);                    // tanh (inf-safe)
            vT_lds[dd * LDK + i] = f2bf(1.f - 2.f / (e2 + 1.f));
        }
    }
    __syncthreads();

    // ---- phase 2: score MFMA. wave w owns m-tile w (rows 16w..16w+15), all 8 n-tiles ----
    f32x4 acc[8];
    #pragma unroll
    for (int nt = 0; nt < 8; ++nt) acc[nt] = (f32x4){0.f, 0.f, 0.f, 0.f};

    #pragma unroll
    for (int ks = 0; ks < 4; ++ks) {
        const bf16x8 a = *(const bf16x8*)&kp_lds[(w * 16 + l16) * LDK + ks * 32 + quad * 8];
        #pragma unroll
        for (int nt = 0; nt < 8; ++nt) {
            const bf16x8 bq8 = *(const bf16x8*)&q_lds[(nt * 16 + l16) * LDK + ks * 32 + quad * 8];
            acc[nt] = __builtin_amdgcn_mfma_f32_16x16x32_bf16(a, bq8, acc[nt], 0, 0, 0);
        }
    }

    // exp + per-column sums (softmax axis = rows i). C/D: col=l16, row=quad*4+reg.
    #pragma unroll
    for (int nt = 0; nt < 8; ++nt) {
        float s = 0.f;
        #pragma unroll
        for (int r = 0; r < 4; ++r) {
            const float e = __expf(acc[nt][r] * SCALE);
            acc[nt][r] = e;
            s += e;
        }
        s += __shfl_xor(s, 16);
        s += __shfl_xor(s, 32);                                   // sum over 16 rows of tile
        if (quad == 0) atomicAdd(&linv[nt * 16 + l16], s);        // ds_add_f32
    }
    __syncthreads();
    if (tid < T) linv[tid] = 1.f / linv[tid];
    __syncthreads();

    // ---- phase 4: fold 1/colsum, write P (bf16) into kp_lds (k is dead) ----
    #pragma unroll
    for (int nt = 0; nt < 8; ++nt) {
        const float li = linv[nt * 16 + l16];
        #pragma unroll
        for (int r = 0; r < 4; ++r) {
            kp_lds[(w * 16 + quad * 4 + r) * LDK + nt * 16 + l16] = f2bf(acc[nt][r] * li);
        }
    }
    __syncthreads();

    // ---- phase 5: PV MFMA. A=P (128x128), B=v^T (K=128, N=32; cols 20..31 zero) ----
    f32x4 yacc[2];
    yacc[0] = (f32x4){0.f, 0.f, 0.f, 0.f};
    yacc[1] = (f32x4){0.f, 0.f, 0.f, 0.f};
    #pragma unroll
    for (int ks = 0; ks < 4; ++ks) {
        const bf16x8 a = *(const bf16x8*)&kp_lds[(w * 16 + l16) * LDK + ks * 32 + quad * 8];
        #pragma unroll
        for (int nt = 0; nt < 2; ++nt) {
            const bf16x8 bv8 = *(const bf16x8*)&vT_lds[(nt * 16 + l16) * LDK + ks * 32 + quad * 8];
            yacc[nt] = __builtin_amdgcn_mfma_f32_16x16x32_bf16(a, bv8, yacc[nt], 0, 0, 0);
        }
    }

    // ---- epilogue: y = PV + x. C/D: row = w*16+quad*4+r, col dd = nt*16+l16 ----
    {
        float* yb = y + (size_t)b * (T * C);
        #pragma unroll
        for (int r = 0; r < 4; ++r) {
            const int row = w * 16 + quad * 4 + r;
            const int base = row * C;
            yb[base + l16] = yacc[0][r] + xb[base + l16];          // dd 0..15
            if (l16 < 4)
                yb[base + 16 + l16] = yacc[1][r] + xb[base + 16 + l16];  // dd 16..19
        }
    }
}

extern "C" void kernel_launch(void* const* d_in, const int* in_sizes, int n_in,
                              void* d_out, int out_size, void* d_ws, size_t ws_size,
                              hipStream_t stream) {
    const float* x  = (const float*)d_in[0];
    const float* Wk = (const float*)d_in[1];
    const float* bk = (const float*)d_in[2];
    const float* Wq = (const float*)d_in[3];
    const float* bq = (const float*)d_in[4];
    const float* Wv = (const float*)d_in[5];
    const float* bv = (const float*)d_in[6];
    float* y = (float*)d_out;
    const int B = in_sizes[0] / (T * C);   // 4096
    sa_fused<<<B, NT, 0, stream>>>(x, Wk, bk, Wq, bq, Wv, bv, y);
}

// Round 4
// 187.300 us; speedup vs baseline: 5.9253x; 1.4622x over previous
//
#include <hip/hip_runtime.h>

#define T 128
#define C 20
#define KQ 100
#define NT 512
#define SCALE 0.08838834764831845f   // 1/sqrt(128)
#define LDP 136   // kp row stride (shorts): 68 dw = 4 mod 32 -> 2-way b128 reads
#define LDQ 120   // q row stride: 60 dw = 28 mod 32 -> 2-way
#define LDV 136   // vT row stride

typedef float  f32x4  __attribute__((ext_vector_type(4)));
typedef short  bf16x8 __attribute__((ext_vector_type(8)));

__device__ __forceinline__ short f2bf(float f) {
    unsigned u = __builtin_bit_cast(unsigned, f);
    unsigned r = (u + 0x7FFFu + ((u >> 16) & 1u)) >> 16;   // RNE
    return (short)r;
}

// ---- prep: transpose/pad weights to bf16 B-fragment layout in d_ws ----
// ws layout: WkT bf16[112][32] @0, WqT @7168B, WvT bf16[32][32] @14336B,
//            bkp f32[112] @16384B, bqp @16832B, bvp f32[32] @17280B
__global__ void prep(const float* __restrict__ Wk, const float* __restrict__ bk,
                     const float* __restrict__ Wq, const float* __restrict__ bq,
                     const float* __restrict__ Wv, const float* __restrict__ bv,
                     short* __restrict__ wkT, short* __restrict__ wqT,
                     short* __restrict__ wvT, float* __restrict__ bkp,
                     float* __restrict__ bqp, float* __restrict__ bvp)
{
    const int t = blockIdx.x * blockDim.x + threadIdx.x;
    if (t < 112 * 32) {
        const int n = t >> 5, c = t & 31;
        const bool ok = (n < KQ) && (c < C);
        wkT[t] = f2bf(ok ? Wk[c * KQ + n] : 0.f);
        wqT[t] = f2bf(ok ? Wq[c * KQ + n] : 0.f);
        if (t < 32 * 32) {
            const int n2 = t >> 5, c2 = t & 31;
            wvT[t] = f2bf((n2 < C && c2 < C) ? Wv[c2 * C + n2] : 0.f);
        }
        if (t < 112) { bkp[t] = t < KQ ? bk[t] : 0.f; bqp[t] = t < KQ ? bq[t] : 0.f; }
        if (t < 32)  bvp[t] = t < C ? bv[t] : 0.f;
    }
}

// One block per batch, 512 threads (8 waves), 73 KB LDS -> 2 blocks/CU.
// ALL matmuls (proj, scores, PV) on MFMA bf16. Weights come pre-transposed
// from d_ws (L2-resident); x A-frags from global, reused across k/q/v.
__global__ __launch_bounds__(NT, 4) void sa_fused(
    const float* __restrict__ x,
    const short* __restrict__ wkT, const short* __restrict__ wqT,
    const short* __restrict__ wvT, const float* __restrict__ bkp,
    const float* __restrict__ bqp, const float* __restrict__ bvp,
    float* __restrict__ y)
{
    __shared__ __align__(16) short kp_lds[T * LDP];   // k [i][d<=111] -> later P [i][j 0..127]
    __shared__ __align__(16) short q_lds [T * LDQ];   // q [j][d<=111]
    __shared__ __align__(16) short vT_lds[32 * LDV];  // v^T [dd][i] (rows 20..31 = 0)
    __shared__ float linv[T];

    const int tid  = threadIdx.x;
    const int lane = tid & 63;
    const int w    = __builtin_amdgcn_readfirstlane(tid >> 6);
    const int quad = lane >> 4;
    const int l16  = lane & 15;
    const int b    = blockIdx.x;
    const float* xb = x + (size_t)b * (T * C);

    if (tid < T) linv[tid] = 0.f;

    // ---- x A-fragment in regs: A[m = w*16+l16][k = quad*8+u], c-pad 20->32 ----
    bf16x8 xa;
    {
        const int i = w * 16 + l16;
        const float* xr = xb + i * C;
        float f[8];
        if (quad < 2) {
            #pragma unroll
            for (int u = 0; u < 8; ++u) f[u] = xr[quad * 8 + u];
        } else if (quad == 2) {
            #pragma unroll
            for (int u = 0; u < 4; ++u) f[u] = xr[16 + u];
            #pragma unroll
            for (int u = 4; u < 8; ++u) f[u] = 0.f;
        } else {
            #pragma unroll
            for (int u = 0; u < 8; ++u) f[u] = 0.f;
        }
        #pragma unroll
        for (int u = 0; u < 8; ++u) xa[u] = f2bf(f[u]);
    }

    // ---- projections on MFMA: wave w owns rows 16w..16w+15 ----
    // k and q: 7 n-tiles each; v: 2 n-tiles. Pad rows of W/b are zero ->
    // elu(0)=0 / tanh(0)=0 pads land automatically.
    #pragma unroll
    for (int nt = 0; nt < 7; ++nt) {
        const bf16x8 wbk = *(const bf16x8*)(wkT + (nt * 16 + l16) * 32 + quad * 8);
        f32x4 ck = __builtin_amdgcn_mfma_f32_16x16x32_bf16(xa, wbk, (f32x4){0.f,0.f,0.f,0.f}, 0, 0, 0);
        const float bb = bkp[nt * 16 + l16];
        #pragma unroll
        for (int r = 0; r < 4; ++r) {
            float e = ck[r] + bb;
            e = e > 0.f ? e : (__expf(e) - 1.f);                  // ELU
            kp_lds[(w * 16 + quad * 4 + r) * LDP + nt * 16 + l16] = f2bf(e);
        }
    }
    #pragma unroll
    for (int nt = 0; nt < 7; ++nt) {
        const bf16x8 wbq = *(const bf16x8*)(wqT + (nt * 16 + l16) * 32 + quad * 8);
        f32x4 cq = __builtin_amdgcn_mfma_f32_16x16x32_bf16(xa, wbq, (f32x4){0.f,0.f,0.f,0.f}, 0, 0, 0);
        const float bb = bqp[nt * 16 + l16];
        #pragma unroll
        for (int r = 0; r < 4; ++r) {
            float e = cq[r] + bb;
            e = e > 0.f ? e : (__expf(e) - 1.f);
            q_lds[(w * 16 + quad * 4 + r) * LDQ + nt * 16 + l16] = f2bf(e);
        }
    }
    #pragma unroll
    for (int nt = 0; nt < 2; ++nt) {
        const bf16x8 wbv = *(const bf16x8*)(wvT + (nt * 16 + l16) * 32 + quad * 8);
        f32x4 cv = __builtin_amdgcn_mfma_f32_16x16x32_bf16(xa, wbv, (f32x4){0.f,0.f,0.f,0.f}, 0, 0, 0);
        const float bb = bvp[nt * 16 + l16];
        #pragma unroll
        for (int r = 0; r < 4; ++r) {
            const float e2 = __expf(2.f * (cv[r] + bb));          // tanh (inf-safe)
            vT_lds[(nt * 16 + l16) * LDV + (w * 16 + quad * 4 + r)] = f2bf(1.f - 2.f / (e2 + 1.f));
        }
    }
    __syncthreads();

    // ---- score MFMA: wave w owns m-tile w, all 8 n-tiles; K = 128 (tail predicated) ----
    f32x4 acc[8];
    #pragma unroll
    for (int nt = 0; nt < 8; ++nt) acc[nt] = (f32x4){0.f, 0.f, 0.f, 0.f};

    #pragma unroll
    for (int ks = 0; ks < 4; ++ks) {
        bf16x8 a = {0,0,0,0,0,0,0,0};
        if (ks < 3 || quad < 2)
            a = *(const bf16x8*)&kp_lds[(w * 16 + l16) * LDP + ks * 32 + quad * 8];
        #pragma unroll
        for (int nt = 0; nt < 8; ++nt) {
            bf16x8 bq8 = {0,0,0,0,0,0,0,0};
            if (ks < 3 || quad < 2)
                bq8 = *(const bf16x8*)&q_lds[(nt * 16 + l16) * LDQ + ks * 32 + quad * 8];
            acc[nt] = __builtin_amdgcn_mfma_f32_16x16x32_bf16(a, bq8, acc[nt], 0, 0, 0);
        }
    }

    // ---- softmax over rows i (axis=1): exp + column sums ----
    #pragma unroll
    for (int nt = 0; nt < 8; ++nt) {
        float s = 0.f;
        #pragma unroll
        for (int r = 0; r < 4; ++r) {
            const float e = __expf(acc[nt][r] * SCALE);
            acc[nt][r] = e;
            s += e;
        }
        s += __shfl_xor(s, 16);
        s += __shfl_xor(s, 32);
        if (quad == 0) atomicAdd(&linv[nt * 16 + l16], s);
    }
    __syncthreads();
    if (tid < T) linv[tid] = 1.f / linv[tid];
    __syncthreads();

    // ---- fold 1/colsum, write P (bf16) over k (dead) ----
    #pragma unroll
    for (int nt = 0; nt < 8; ++nt) {
        const float li = linv[nt * 16 + l16];
        #pragma unroll
        for (int r = 0; r < 4; ++r)
            kp_lds[(w * 16 + quad * 4 + r) * LDP + nt * 16 + l16] = f2bf(acc[nt][r] * li);
    }
    __syncthreads();

    // ---- PV MFMA: A = P (K = j = 128), B = v^T (N = 32, cols 20..31 zero) ----
    f32x4 yacc[2];
    yacc[0] = (f32x4){0.f, 0.f, 0.f, 0.f};
    yacc[1] = (f32x4){0.f, 0.f, 0.f, 0.f};
    #pragma unroll
    for (int ks = 0; ks < 4; ++ks) {
        const bf16x8 a = *(const bf16x8*)&kp_lds[(w * 16 + l16) * LDP + ks * 32 + quad * 8];
        #pragma unroll
        for (int nt = 0; nt < 2; ++nt) {
            const bf16x8 bv8 = *(const bf16x8*)&vT_lds[(nt * 16 + l16) * LDV + ks * 32 + quad * 8];
            yacc[nt] = __builtin_amdgcn_mfma_f32_16x16x32_bf16(a, bv8, yacc[nt], 0, 0, 0);
        }
    }

    // ---- epilogue: y = PV + x ----
    {
        float* yb = y + (size_t)b * (T * C);
        #pragma unroll
        for (int r = 0; r < 4; ++r) {
            const int row  = w * 16 + quad * 4 + r;
            const int base = row * C;
            yb[base + l16] = yacc[0][r] + xb[base + l16];
            if (l16 < 4)
                yb[base + 16 + l16] = yacc[1][r] + xb[base + 16 + l16];
        }
    }
}

extern "C" void kernel_launch(void* const* d_in, const int* in_sizes, int n_in,
                              void* d_out, int out_size, void* d_ws, size_t ws_size,
                              hipStream_t stream) {
    const float* x  = (const float*)d_in[0];
    const float* Wk = (const float*)d_in[1];
    const float* bk = (const float*)d_in[2];
    const float* Wq = (const float*)d_in[3];
    const float* bq = (const float*)d_in[4];
    const float* Wv = (const float*)d_in[5];
    const float* bv = (const float*)d_in[6];
    float* y = (float*)d_out;

    char* ws = (char*)d_ws;
    short* wkT = (short*)ws;                 // [112][32] bf16
    short* wqT = (short*)(ws + 7168);        // [112][32] bf16
    short* wvT = (short*)(ws + 14336);       // [32][32]  bf16
    float* bkp = (float*)(ws + 16384);       // [112]
    float* bqp = (float*)(ws + 16832);       // [112]
    float* bvp = (float*)(ws + 17280);       // [32]

    prep<<<14, 256, 0, stream>>>(Wk, bk, Wq, bq, Wv, bv, wkT, wqT, wvT, bkp, bqp, bvp);

    const int B = in_sizes[0] / (T * C);     // 4096
    sa_fused<<<B, NT, 0, stream>>>(x, wkT, wqT, wvT, bkp, bqp, bvp, y);
}